// Round 15
// baseline (352.919 us; speedup 1.0000x reference)
//
#include <hip/hip_runtime.h>
#include <hip/hip_bf16.h>
#include <math.h>

// ---------------------------------------------------------------------------
// CapsuleNetwork forward.
// FAST PATH (ws >= 116,391,936 B): pcaps conv = fused-im2col split-bf16 MFMA,
// ic-major K-order. R15: 1024-thr gemm (16 waves = og4 x khQ4) for 8 waves/SIMD.
//   conv1b : img -> xH0/xL0 [128][256][400] bf16 hi/lo
//   xsplit3: xH0/xL0 -> xTh/xTl layout [128 b][32 cc][400 pos][8 ic]
//   wsplit2: pcaps_w -> Wf hi/lo [qc=32][T=41][256 oc][2 h][8 ic], tap=2T+h
//   gemm8  : 576 blocks = 72 mt(64 rows) x 8 q(32-ic group). 16 waves =
//            og(4: 64 oc) x khQ(4: T quarters {0,10,20,30}..{10,20,30,41}).
//            Per icchunk: stage A rows (swizzle sigma(r)=r^((r>>3)&7), linear
//            LDS dest / pre-swizzled global src). 4 ds + 4 W + 12 MFMA per T.
//            kh tree-reduce via LDS (1->0 || 3->2, then 2->0), kh0 writes C.
//   squash(nq=8) -> u ; routing v2 -> out
// FALLBACK: R5 fp32 direct-conv path.
// ---------------------------------------------------------------------------

typedef __attribute__((ext_vector_type(8)))  short  short8;
typedef __attribute__((ext_vector_type(8)))  ushort ushort8v;
typedef __attribute__((ext_vector_type(16))) float  f32x16;
#define MFMA32(a, b, c) __builtin_amdgcn_mfma_f32_32x32x16_bf16(a, b, c, 0, 0, 0)

__device__ __forceinline__ void split_bf16(float v, ushort& h, ushort& l) {
    __hip_bfloat16 hb = __float2bfloat16(v);
    float hf = __bfloat162float(hb);
    __hip_bfloat16 lb = __float2bfloat16(v - hf);
    h = *reinterpret_cast<ushort*>(&hb);
    l = *reinterpret_cast<ushort*>(&lb);
}

__device__ __forceinline__ void gl_lds16(const void* g, const void* lds_uniform_base) {
    __builtin_amdgcn_global_load_lds(
        (const __attribute__((address_space(1))) void*)g,
        (__attribute__((address_space(3))) void*)lds_uniform_base,
        16, 0, 0);
}

__device__ __forceinline__ int sigr(int r) { return r ^ ((r >> 3) & 7); }

// ------------------------------- conv1b ------------------------------------
__global__ __launch_bounds__(256) void conv1b_kernel(
    const float* __restrict__ img, const float* __restrict__ w,
    const float* __restrict__ bias, ushort* __restrict__ xH0, ushort* __restrict__ xL0)
{
    const int ct = blockIdx.x;
    const int b  = blockIdx.y;
    const int t  = threadIdx.x;
    __shared__ float img_s[784];
    __shared__ float w_s[64 * 81];
    for (int idx = t; idx < 784; idx += 256) img_s[idx] = img[b * 784 + idx];
    for (int idx = t; idx < 64 * 81; idx += 256) w_s[idx] = w[ct * 64 * 81 + idx];
    __syncthreads();
    for (int task = t; task < 1280; task += 256) {
        const int cl = task / 20;
        const int oy = task - cl * 20;
        float acc[20];
        const float bv = bias[ct * 64 + cl];
#pragma unroll
        for (int j = 0; j < 20; ++j) acc[j] = bv;
#pragma unroll
        for (int ky = 0; ky < 9; ++ky) {
            float rowv[28];
            const float* r = &img_s[(oy + ky) * 28];
#pragma unroll
            for (int j = 0; j < 28; ++j) rowv[j] = r[j];
#pragma unroll
            for (int kx = 0; kx < 9; ++kx) {
                const float wv = w_s[cl * 81 + ky * 9 + kx];
#pragma unroll
                for (int j = 0; j < 20; ++j) acc[j] += wv * rowv[j + kx];
            }
        }
        const size_t row = ((size_t)b * 256 + ct * 64 + cl) * 400 + oy * 20;
        uint* ph = (uint*)(xH0 + row);
        uint* pl = (uint*)(xL0 + row);
#pragma unroll
        for (int j = 0; j < 10; ++j) {
            ushort h0, l0, h1, l1;
            split_bf16(fmaxf(acc[2 * j], 0.f), h0, l0);
            split_bf16(fmaxf(acc[2 * j + 1], 0.f), h1, l1);
            ph[j] = (uint)h0 | ((uint)h1 << 16);
            pl[j] = (uint)l0 | ((uint)l1 << 16);
        }
    }
}

// ------------------------------ xsplit3 ------------------------------------
__global__ __launch_bounds__(256) void xsplit3_kernel(
    const ushort* __restrict__ xH0, const ushort* __restrict__ xL0,
    ushort* __restrict__ xTh, ushort* __restrict__ xTl)
{
    const int b   = blockIdx.x;   // 128
    const int icb = blockIdx.y;   // 8 (32 ic each = 4 cc chunks)
    const int t   = threadIdx.x;
    __shared__ ushort xs[32 * 408];
#pragma unroll
    for (int pol = 0; pol < 2; ++pol) {
        const ushort* src = pol ? xL0 : xH0;
        ushort* dst = pol ? xTl : xTh;
        if (pol) __syncthreads();
        for (int idx = t; idx < 12800; idx += 256) {
            const int ic = idx / 400;
            const int p  = idx - ic * 400;
            xs[ic * 408 + p] = src[((size_t)b * 256 + icb * 32 + ic) * 400 + p];
        }
        __syncthreads();
        for (int u = t; u < 1600; u += 256) {
            const int c = u / 400;
            const int p = u - c * 400;
            ushort8v v;
#pragma unroll
            for (int j = 0; j < 8; ++j) v[j] = xs[(c * 8 + j) * 408 + p];
            const int cc = icb * 4 + c;
            *(ushort8v*)(dst + (((size_t)b * 32 + cc) * 400 + p) * 8) = v;
        }
    }
}

// ------------------------------ wsplit2 ------------------------------------
__global__ __launch_bounds__(256) void wsplit2_kernel(
    const float* __restrict__ pw, ushort* __restrict__ Wfh, ushort* __restrict__ Wfl)
{
    const int oc = blockIdx.x;    // 256
    const int t  = threadIdx.x;
    __shared__ float buf[648];
    const float* row = pw + (size_t)oc * 20736;
    for (int qc = 0; qc < 32; ++qc) {
        __syncthreads();
        for (int idx = t; idx < 648; idx += 256) buf[idx] = row[qc * 648 + idx];
        __syncthreads();
        if (t < 82) {
            const int T  = t >> 1;
            const int hh = t & 1;
            const int tap = 2 * T + hh;
            ushort8v h8, l8;
#pragma unroll
            for (int j = 0; j < 8; ++j) {
                const float v = (tap <= 80) ? buf[j * 81 + tap] : 0.f;
                ushort hb, lb;
                split_bf16(v, hb, lb);
                h8[j] = hb; l8[j] = lb;
            }
            const size_t rec = (((size_t)(qc * 41 + T) * 256 + oc) * 2 + hh) * 8;
            *(ushort8v*)(Wfh + rec) = h8;
            *(ushort8v*)(Wfl + rec) = l8;
        }
    }
}

// ------------------------------- gemm8 -------------------------------------
__global__ __launch_bounds__(1024) void gemm8_kernel(
    const ushort* __restrict__ xTh, const ushort* __restrict__ xTl,
    const ushort* __restrict__ Wfh, const ushort* __restrict__ Wfl,
    float* __restrict__ part)
{
    const int bid = blockIdx.x;          // 576
    const int q = bid & 7, mt = bid >> 3;
    const int t = threadIdx.x;           // 0..1023
    const int w = t >> 6, lane = t & 63;
    const int ln = lane & 31, h = lane >> 5;
    const int og = w & 3, kh = w >> 2;   // og 0..3, kh 0..3 (T quarter)

    __shared__ ushort As[20480];         // 40,960 B: hi slots [0,1200), lo [1280,2480)

    const int m_base = mt * 64;
    const int bmin = m_base / 36;

    // staging source byte offsets: round0 slot j=t, round1 slot j=1024+t (t<176)
    uint soff0, soff1;
    {
        int j = t;
        int rbj = j / 400;
        int gp  = sigr(j) - rbj * 400;   // sigma stays in same 400-block (400%8==0)
        soff0 = (uint)((bmin + rbj) * 204800 + q * 25600 + gp * 16);
        j = t + 1024; if (j >= 1200) j = 0;
        rbj = j / 400;
        gp  = sigr(j) - rbj * 400;
        soff1 = (uint)((bmin + rbj) * 204800 + q * 25600 + gp * 16);
    }

    int pb0, pb1;
    {
        int m = m_base + ln;
        int b = m / 36, pos = m - b * 36;
        pb0 = (b - bmin) * 400 + (pos / 6) * 40 + (pos % 6) * 2;
        m += 32;
        b = m / 36; pos = m - b * 36;
        pb1 = (b - bmin) * 400 + (pos / 6) * 40 + (pos % 6) * 2;
    }

    const int T0 = 10 * kh;
    const int T1 = (kh == 3) ? 41 : 10 * kh + 10;
    const int tap_init = 2 * T0 + h;
    const int ky0 = tap_init / 9, kx0 = tap_init - 9 * ky0;
    const int off_init = ky0 * 20 + kx0;

    const uint wlane = (uint)((og * 64 + ln) * 16 + h * 8);

    f32x16 acc00, acc01, acc10, acc11;
#pragma unroll
    for (int i = 0; i < 16; ++i) { acc00[i] = 0.f; acc01[i] = 0.f; acc10[i] = 0.f; acc11[i] = 0.f; }

#define G8_STAGE(c_)                                                           \
    {                                                                          \
        const uint cc = (uint)(c_) * 6400u;                                    \
        const uint db = (uint)(w * 64) * 16;                                   \
        gl_lds16((const char*)xTh + soff0 + cc, (char*)As + db);               \
        gl_lds16((const char*)xTl + soff0 + cc, (char*)As + 1280 * 16 + db);   \
        if (t < 176) {                                                         \
            gl_lds16((const char*)xTh + soff1 + cc, (char*)As + 1024 * 16 + db);          \
            gl_lds16((const char*)xTl + soff1 + cc, (char*)As + (1280 + 1024) * 16 + db); \
        }                                                                      \
    }

    for (int c = 0; c < 4; ++c) {
        if (c > 0) __syncthreads();     // previous icchunk's readers done
        G8_STAGE(c);
        __syncthreads();                // implicit vmcnt(0): stage visible

        const size_t rec0 = ((size_t)(q * 4 + c) * 41 + T0) * 4096;
        const ushort* wph = Wfh + rec0 + wlane;
        const ushort* wpl = Wfl + rec0 + wlane;
        short8 cw0h = *(const short8*)(wph);
        short8 cw1h = *(const short8*)(wph + 512);    // +32 oc (oc stride 16)
        short8 cw0l = *(const short8*)(wpl);
        short8 cw1l = *(const short8*)(wpl + 512);

        int off = off_init;
        int kxc = kx0;
        for (int T = T0; T < T1; ++T) {
            const int step = (T + 1 < T1) ? 4096 : 0;
            const short8 nw0h = *(const short8*)(wph + step);
            const short8 nw1h = *(const short8*)(wph + step + 512);
            const short8 nw0l = *(const short8*)(wpl + step);
            const short8 nw1l = *(const short8*)(wpl + step + 512);
            const int s0 = sigr(pb0 + off);
            const int s1 = sigr(pb1 + off);
            const short8 a0h = *(const short8*)(As + s0 * 8);
            const short8 a0l = *(const short8*)(As + (1280 + s0) * 8);
            const short8 a1h = *(const short8*)(As + s1 * 8);
            const short8 a1l = *(const short8*)(As + (1280 + s1) * 8);
            acc00 = MFMA32(a0h, cw0h, acc00);
            acc00 = MFMA32(a0l, cw0h, acc00);
            acc00 = MFMA32(a0h, cw0l, acc00);
            acc01 = MFMA32(a0h, cw1h, acc01);
            acc01 = MFMA32(a0l, cw1h, acc01);
            acc01 = MFMA32(a0h, cw1l, acc01);
            acc10 = MFMA32(a1h, cw0h, acc10);
            acc10 = MFMA32(a1l, cw0h, acc10);
            acc10 = MFMA32(a1h, cw0l, acc10);
            acc11 = MFMA32(a1h, cw1h, acc11);
            acc11 = MFMA32(a1l, cw1h, acc11);
            acc11 = MFMA32(a1h, cw1l, acc11);
            cw0h = nw0h; cw1h = nw1h; cw0l = nw0l; cw1l = nw1l;
            wph += step; wpl += step;
            const bool wrap = (kxc >= 7);
            off += wrap ? 13 : 2;
            kxc += wrap ? -7 : 2;
        }
    }
#undef G8_STAGE

    // ---- kh tree reduce via LDS: (kh1->kh0 || kh3->kh2), then kh2->kh0 ----
    float4* red = (float4*)As;           // 2560 float4 capacity; use 2048
    const int cidx = og * 64 + lane;     // 0..255

#define RED_A(AX)                                                              \
    __syncthreads();                                                           \
    if (kh == 1) {                                                             \
        _Pragma("unroll") for (int e = 0; e < 4; ++e)                          \
            red[e * 256 + cidx] = make_float4(AX[e*4], AX[e*4+1], AX[e*4+2], AX[e*4+3]); \
    } else if (kh == 3) {                                                      \
        _Pragma("unroll") for (int e = 0; e < 4; ++e)                          \
            red[1024 + e * 256 + cidx] = make_float4(AX[e*4], AX[e*4+1], AX[e*4+2], AX[e*4+3]); \
    }                                                                          \
    __syncthreads();                                                           \
    if (kh == 0) {                                                             \
        _Pragma("unroll") for (int e = 0; e < 4; ++e) {                        \
            const float4 v = red[e * 256 + cidx];                              \
            AX[e*4] += v.x; AX[e*4+1] += v.y; AX[e*4+2] += v.z; AX[e*4+3] += v.w; } \
    } else if (kh == 2) {                                                      \
        _Pragma("unroll") for (int e = 0; e < 4; ++e) {                        \
            const float4 v = red[1024 + e * 256 + cidx];                       \
            AX[e*4] += v.x; AX[e*4+1] += v.y; AX[e*4+2] += v.z; AX[e*4+3] += v.w; } \
    }

#define RED_B(AX)                                                              \
    __syncthreads();                                                           \
    if (kh == 2) {                                                             \
        _Pragma("unroll") for (int e = 0; e < 4; ++e)                          \
            red[e * 256 + cidx] = make_float4(AX[e*4], AX[e*4+1], AX[e*4+2], AX[e*4+3]); \
    }                                                                          \
    __syncthreads();                                                           \
    if (kh == 0) {                                                             \
        _Pragma("unroll") for (int e = 0; e < 4; ++e) {                        \
            const float4 v = red[e * 256 + cidx];                              \
            AX[e*4] += v.x; AX[e*4+1] += v.y; AX[e*4+2] += v.z; AX[e*4+3] += v.w; } \
    }

    RED_A(acc00) RED_A(acc01) RED_A(acc10) RED_A(acc11)
    RED_B(acc00) RED_B(acc01) RED_B(acc10) RED_B(acc11)
#undef RED_A
#undef RED_B

    if (kh == 0) {
        // epilogue: C[m][oc] -> part[q][b][cap][pos][d]
        float* pq = part + (size_t)q * 1179648;
#pragma unroll
        for (int mf = 0; mf < 2; ++mf) {
#pragma unroll
            for (int nf = 0; nf < 2; ++nf) {
                const f32x16 a = (mf == 0) ? (nf == 0 ? acc00 : acc01)
                                           : (nf == 0 ? acc10 : acc11);
                const int oc = og * 64 + nf * 32 + ln;
                float* pb = pq + (oc >> 3) * 288 + (oc & 7);
#pragma unroll
                for (int r = 0; r < 16; ++r) {
                    const int m = m_base + mf * 32 + (r & 3) + 8 * (r >> 2) + 4 * h;
                    const int b = m / 36;
                    const int pos = m - b * 36;
                    pb[(size_t)b * 9216 + pos * 8] = a[r];
                }
            }
        }
    }
}

// ------------------------------- squash ------------------------------------
__global__ __launch_bounds__(256) void squash_kernel(
    const float* __restrict__ part, const float* __restrict__ bias,
    float* __restrict__ u, int nq)
{
    const int idx = blockIdx.x * 256 + threadIdx.x;
    if (idx >= 128 * 1152) return;
    const int i   = idx % 1152;
    const int cap = i / 36;
    float v[8];
    float n2 = 0.f;
#pragma unroll
    for (int c = 0; c < 8; ++c) {
        float s = bias[cap * 8 + c];
        for (int qq = 0; qq < nq; ++qq) s += part[(size_t)qq * 1179648 + (size_t)idx * 8 + c];
        v[c] = s;
        n2 += s * s;
    }
    const float sc = sqrtf(n2) / (1.f + n2);
#pragma unroll
    for (int c = 0; c < 8; ++c) u[(size_t)idx * 8 + c] = v[c] * sc;
}

// ------------------------------- routing v2 --------------------------------
__device__ __forceinline__ float4 uhat4(const float* __restrict__ urow,
                                        const float* __restrict__ wrow)
{
    float ur[8];
    const float4 u0 = *(const float4*)urow;
    const float4 u1 = *(const float4*)(urow + 4);
    ur[0] = u0.x; ur[1] = u0.y; ur[2] = u0.z; ur[3] = u0.w;
    ur[4] = u1.x; ur[5] = u1.y; ur[6] = u1.z; ur[7] = u1.w;
    float4 uh = make_float4(0.f, 0.f, 0.f, 0.f);
#pragma unroll
    for (int c = 0; c < 8; ++c) {
        const float4 wv = *(const float4*)(wrow + c * 16);
        uh.x += ur[c] * wv.x; uh.y += ur[c] * wv.y;
        uh.z += ur[c] * wv.z; uh.w += ur[c] * wv.w;
    }
    return uh;
}

__device__ __forceinline__ float4 uh_from_lds(const ushort* uhs, int i, int d4)
{
    const uint2 rv = *(const uint2*)(uhs + i * 16 + d4);
    float4 r;
    r.x = __uint_as_float((rv.x & 0xffffu) << 16);
    r.y = __uint_as_float((rv.x >> 16) << 16);
    r.z = __uint_as_float((rv.y & 0xffffu) << 16);
    r.w = __uint_as_float((rv.y >> 16) << 16);
    return r;
}

__global__ __launch_bounds__(256) void routing_kernel(
    const float* __restrict__ u, const float* __restrict__ rw,
    float* __restrict__ out)
{
    const int b = blockIdx.x;
    const int o = blockIdx.y;
    const int t = threadIdx.x;
    __shared__ ushort uh_s[1152 * 16];
    __shared__ float logits[1152];
    __shared__ float ebuf[1152];
    __shared__ float psum[64][17];
    __shared__ float red[8];
    __shared__ float v_s[16];
    const float* ub = u + (size_t)b * 9216;
    const float* wo = rw + (size_t)o * 147456;
    for (int i = t; i < 1152; i += 256) logits[i] = 0.f;
    __syncthreads();
    const int dq = t & 3;
    const int ig = t >> 2;
    const int d4 = dq * 4;
    for (int iter = 1; iter <= 3; ++iter) {
        float lmax = -3.0e38f;
        for (int i = t; i < 1152; i += 256) lmax = fmaxf(lmax, logits[i]);
#pragma unroll
        for (int off = 32; off; off >>= 1) lmax = fmaxf(lmax, __shfl_xor(lmax, off, 64));
        if ((t & 63) == 0) red[t >> 6] = lmax;
        __syncthreads();
        const float m = fmaxf(fmaxf(red[0], red[1]), fmaxf(red[2], red[3]));
        float ls = 0.f;
        for (int i = t; i < 1152; i += 256) {
            const float e = expf(logits[i] - m);
            ebuf[i] = e;
            ls += e;
        }
#pragma unroll
        for (int off = 32; off; off >>= 1) ls += __shfl_xor(ls, off, 64);
        if ((t & 63) == 0) red[4 + (t >> 6)] = ls;
        __syncthreads();
        const float sumE = red[4] + red[5] + red[6] + red[7];
        float4 ps = make_float4(0.f, 0.f, 0.f, 0.f);
        if (iter == 1) {
            for (int i = ig; i < 1152; i += 64) {
                const float4 uh = uhat4(ub + i * 8, wo + (size_t)i * 128 + d4);
                ushort4 hb;
                __hip_bfloat16 q0 = __float2bfloat16(uh.x);
                __hip_bfloat16 q1 = __float2bfloat16(uh.y);
                __hip_bfloat16 q2 = __float2bfloat16(uh.z);
                __hip_bfloat16 q3 = __float2bfloat16(uh.w);
                hb.x = *(ushort*)&q0; hb.y = *(ushort*)&q1;
                hb.z = *(ushort*)&q2; hb.w = *(ushort*)&q3;
                *(ushort4*)(uh_s + i * 16 + d4) = hb;
                const float e = ebuf[i];
                ps.x += e * uh.x; ps.y += e * uh.y; ps.z += e * uh.z; ps.w += e * uh.w;
            }
        } else {
            for (int i = ig; i < 1152; i += 64) {
                const float4 uh = uh_from_lds(uh_s, i, d4);
                const float e = ebuf[i];
                ps.x += e * uh.x; ps.y += e * uh.y; ps.z += e * uh.z; ps.w += e * uh.w;
            }
        }
        psum[ig][d4 + 0] = ps.x; psum[ig][d4 + 1] = ps.y;
        psum[ig][d4 + 2] = ps.z; psum[ig][d4 + 3] = ps.w;
        __syncthreads();
        if (t < 16) {
            float s = 0.f;
            for (int g = 0; g < 64; ++g) s += psum[g][t];
            s /= sumE;
            float qn = s * s;
            qn += __shfl_xor(qn, 1, 16); qn += __shfl_xor(qn, 2, 16);
            qn += __shfl_xor(qn, 4, 16); qn += __shfl_xor(qn, 8, 16);
            v_s[t] = s * sqrtf(qn) / (1.f + qn);
        }
        __syncthreads();
        if (iter < 3) {
            const float v0 = v_s[d4 + 0], v1 = v_s[d4 + 1];
            const float v2 = v_s[d4 + 2], v3 = v_s[d4 + 3];
            for (int i = ig; i < 1152; i += 64) {
                const float4 uh = uh_from_lds(uh_s, i, d4);
                float pr = uh.x * v0 + uh.y * v1 + uh.z * v2 + uh.w * v3;
                pr += __shfl_xor(pr, 1, 64);
                pr += __shfl_xor(pr, 2, 64);
                if (dq == 0) logits[i] += pr;
            }
            __syncthreads();
        }
    }
    if (t < 16) out[((size_t)b * 10 + o) * 16 + t] = v_s[t];
}

// ===================== FALLBACK (R5 fp32 direct conv) ======================
#define WSL4 1344

__global__ __launch_bounds__(256) void conv1_kernel(
    const float* __restrict__ img, const float* __restrict__ w,
    const float* __restrict__ bias, float* __restrict__ x)
{
    const int ct = blockIdx.x;
    const int b  = blockIdx.y;
    const int t  = threadIdx.x;
    __shared__ float img_s[784];
    __shared__ float w_s[64 * 81];
    for (int idx = t; idx < 784; idx += 256) img_s[idx] = img[b * 784 + idx];
    for (int idx = t; idx < 64 * 81; idx += 256) w_s[idx] = w[ct * 64 * 81 + idx];
    __syncthreads();
    for (int task = t; task < 1280; task += 256) {
        const int cl = task / 20;
        const int oy = task - cl * 20;
        float acc[20];
        const float bv = bias[ct * 64 + cl];
#pragma unroll
        for (int j = 0; j < 20; ++j) acc[j] = bv;
#pragma unroll
        for (int ky = 0; ky < 9; ++ky) {
            float rowv[28];
            const float* r = &img_s[(oy + ky) * 28];
#pragma unroll
            for (int j = 0; j < 28; ++j) rowv[j] = r[j];
#pragma unroll
            for (int kx = 0; kx < 9; ++kx) {
                const float wv = w_s[cl * 81 + ky * 9 + kx];
#pragma unroll
                for (int j = 0; j < 20; ++j) acc[j] += wv * rowv[j + kx];
            }
        }
        float* xp = x + (((size_t)b * 256 + ct * 64 + cl) * 400) + oy * 20;
#pragma unroll
        for (int j = 0; j < 20; ++j) xp[j] = fmaxf(acc[j], 0.f);
    }
}

__global__ __launch_bounds__(256) void wtrans_kernel(
    const float* __restrict__ w, float* __restrict__ wT)
{
    const int idx = blockIdx.x * 256 + threadIdx.x;
    if (idx >= 4 * 256 * 81 * 16) return;
    const int c      = idx & 15;
    const int k      = (idx >> 4) % 81;
    const int ic     = ((idx >> 4) / 81) % 256;
    const int octile = idx / (16 * 81 * 256);
    const int ocb    = octile * 64 + c * 4;
    float4 v;
    v.x = w[((size_t)(ocb + 0) * 256 + ic) * 81 + k];
    v.y = w[((size_t)(ocb + 1) * 256 + ic) * 81 + k];
    v.z = w[((size_t)(ocb + 2) * 256 + ic) * 81 + k];
    v.w = w[((size_t)(ocb + 3) * 256 + ic) * 81 + k];
    ((float4*)wT)[((size_t)octile * 256 + ic) * WSL4 + k * 16 + c] = v;
}

__global__ __launch_bounds__(384) void pcaps_kernel(
    const float* __restrict__ x, const float* __restrict__ wT,
    float* __restrict__ part)
{
    const int btile  = blockIdx.x;
    const int octile = blockIdx.y;
    const int ict    = blockIdx.z;
    const int t    = threadIdx.x;
    const int wave = t >> 6;
    const int lane = t & 63;
    __shared__ float4 w_s[2][WSL4];
    __shared__ float4 x_s[2][448];
    const int oc4  = (t & 15) * 4;
    const int slot = t >> 4;
    const int bb   = slot / 6;
    const int oy   = slot - 6 * bb;
    const int b0   = btile * 4;
    float acc[6][4];
#pragma unroll
    for (int p = 0; p < 6; ++p) {
        acc[p][0] = 0.f; acc[p][1] = 0.f; acc[p][2] = 0.f; acc[p][3] = 0.f;
    }
    const float*  xg   = x + (size_t)b0 * 102400 + (size_t)ict * 25600;
    const float4* wsrc = (const float4*)wT + ((size_t)octile * 256 + ict * 64) * WSL4;
#define PCAPS_STAGE(bf_, ic_)                                                  \
    {                                                                          \
        const float4* gsl = wsrc + (size_t)(ic_) * WSL4;                       \
        for (int ch = wave; ch < 21; ch += 6)                                  \
            gl_lds16(gsl + ch * 64 + lane, &w_s[bf_][ch * 64]);                \
        for (int ch = wave; ch < 7; ch += 6) {                                 \
            int idx = ch * 64 + lane;                                          \
            if (idx >= 400) idx = 0;                                           \
            const int xbb = idx / 100;                                         \
            const int off = idx - xbb * 100;                                   \
            const float* g = xg + (size_t)xbb * 102400 + (ic_) * 400 + off * 4;\
            gl_lds16(g, &x_s[bf_][ch * 64]);                                   \
        }                                                                      \
    }
    PCAPS_STAGE(0, 0);
    __syncthreads();
    int buf = 0;
    for (int ic = 0; ic < 64; ++ic) {
        if (ic < 63) PCAPS_STAGE(buf ^ 1, ic + 1);
        const float* xrow = (const float*)x_s[buf] + bb * 400;
        const float* wrow = (const float*)w_s[buf];
#pragma unroll
        for (int ky = 0; ky < 9; ++ky) {
            float rowv[20];
            const float4* xr = (const float4*)&xrow[(2 * oy + ky) * 20];
#pragma unroll
            for (int j = 0; j < 5; ++j) ((float4*)rowv)[j] = xr[j];
#pragma unroll
            for (int kx = 0; kx < 9; ++kx) {
                const float4 wv = *(const float4*)&wrow[(ky * 9 + kx) * 64 + oc4];
#pragma unroll
                for (int p = 0; p < 6; ++p) {
                    const float xv = rowv[2 * p + kx];
                    acc[p][0] += xv * wv.x; acc[p][1] += xv * wv.y;
                    acc[p][2] += xv * wv.z; acc[p][3] += xv * wv.w;
                }
            }
        }
        __syncthreads();
        buf ^= 1;
    }
#undef PCAPS_STAGE
    float* pb = part + ((size_t)ict * 128 + (b0 + bb)) * 9216;
    const int oc0 = octile * 64 + oc4;
    const int cap = oc0 >> 3;
    const int d0  = oc0 & 7;
#pragma unroll
    for (int p = 0; p < 6; ++p) {
        const int pos = oy * 6 + p;
        *(float4*)&pb[((size_t)cap * 36 + pos) * 8 + d0] =
            make_float4(acc[p][0], acc[p][1], acc[p][2], acc[p][3]);
    }
}

// ------------------------------- launcher ----------------------------------
extern "C" void kernel_launch(void* const* d_in, const int* in_sizes, int n_in,
                              void* d_out, int out_size, void* d_ws, size_t ws_size,
                              hipStream_t stream)
{
    const float* img = (const float*)d_in[0];
    const float* c1w = (const float*)d_in[1];
    const float* c1b = (const float*)d_in[2];
    const float* pw  = (const float*)d_in[3];
    const float* pb  = (const float*)d_in[4];
    const float* rw  = (const float*)d_in[5];
    float* out = (float*)d_out;
    char* ws = (char*)d_ws;

    if (ws_size >= 116391936ULL) {
        // fast path (116,391,936 B) — lifetime map in header comment.
        ushort* xTh  = (ushort*)(ws);                  // [0, 26,214,400)
        ushort* xTl  = (ushort*)(ws + 26214400);       // [26,214,400, 52,428,800)
        ushort* xH0  = (ushort*)(ws + 52428800);       // dead after xsplit3
        ushort* xL0  = (ushort*)(ws + 78643200);       // dead after xsplit3
        ushort* Wfh  = (ushort*)(ws + 52428800);       // aliases dead xH0
        ushort* Wfl  = (ushort*)(ws + 63176704);
        float*  part = (float*)(ws + 73924608);        // aliases dead xL0
        float*  u    = (float*)(ws + 111673344);
        hipLaunchKernelGGL(conv1b_kernel, dim3(4, 128), dim3(256), 0, stream, img, c1w, c1b, xH0, xL0);
        hipLaunchKernelGGL(xsplit3_kernel, dim3(128, 8), dim3(256), 0, stream, xH0, xL0, xTh, xTl);
        hipLaunchKernelGGL(wsplit2_kernel, dim3(256), dim3(256), 0, stream, pw, Wfh, Wfl);   // after xsplit3!
        hipLaunchKernelGGL(gemm8_kernel, dim3(576), dim3(1024), 0, stream, xTh, xTl, Wfh, Wfl, part);
        hipLaunchKernelGGL(squash_kernel, dim3(576), dim3(256), 0, stream, part, pb, u, 8);
        hipLaunchKernelGGL(routing_kernel, dim3(128, 10), dim3(256), 0, stream, u, rw, out);
    } else {
        // fallback: R5 fp32 direct conv (97.9 MB, proven)
        float* x    = (float*)(ws);
        float* part = (float*)(ws + 52428800);
        float* u    = (float*)(ws + 52428800 + 18874368);
        float* wT   = (float*)(ws + 52428800 + 18874368 + 4718592);
        hipLaunchKernelGGL(wtrans_kernel, dim3((4 * 256 * 81 * 16 + 255) / 256), dim3(256), 0, stream, pw, wT);
        hipLaunchKernelGGL(conv1_kernel, dim3(4, 128), dim3(256), 0, stream, img, c1w, c1b, x);
        hipLaunchKernelGGL(pcaps_kernel, dim3(32, 4, 4), dim3(384), 0, stream, x, wT, part);
        hipLaunchKernelGGL(squash_kernel, dim3(576), dim3(256), 0, stream, part, pb, u, 4);
        hipLaunchKernelGGL(routing_kernel, dim3(128, 10), dim3(256), 0, stream, u, rw, out);
    }
}

// Round 16
// 328.464 us; speedup vs baseline: 1.0745x; 1.0745x over previous
//
#include <hip/hip_runtime.h>
#include <hip/hip_bf16.h>
#include <math.h>

// ---------------------------------------------------------------------------
// CapsuleNetwork forward.
// FAST PATH (ws >= 116,391,936 B): pcaps conv = fused-im2col split-bf16 MFMA,
// ic-major K-order. R16: 256-thr gemm, 4 waves = og only (no kh split),
// register double-buffered A (LDS) and W (L2) so the matrix pipe never waits.
//   conv1b : img -> xH0/xL0 [128][256][400] bf16 hi/lo
//   xsplit3: xH0/xL0 -> xTh/xTl layout [128 b][32 cc][400 pos][8 ic]
//   wsplit2: pcaps_w -> Wf hi/lo [qc=32][T=41][256 oc][2 h][8 ic], tap=2T+h
//   gemm9  : 576 blocks = 72 mt(64 rows) x 8 q(32-ic group). 4 waves (64 oc
//            each); each wave walks all 41 T x 4 icchunks. Per icchunk: stage
//            A rows (swizzle sigma(r)=r^((r>>3)&7), linear LDS dest /
//            pre-swizzled global src). Per T: 12 MFMA on current regs while
//            prefetching T+1's 4 A ds_reads + 4 W loads into registers.
//            No reduce phase; each wave writes its 64-oc slice directly.
//   squash(nq=8) -> u ; routing v2 -> out
// FALLBACK: R5 fp32 direct-conv path.
// ---------------------------------------------------------------------------

typedef __attribute__((ext_vector_type(8)))  short  short8;
typedef __attribute__((ext_vector_type(8)))  ushort ushort8v;
typedef __attribute__((ext_vector_type(16))) float  f32x16;
#define MFMA32(a, b, c) __builtin_amdgcn_mfma_f32_32x32x16_bf16(a, b, c, 0, 0, 0)

__device__ __forceinline__ void split_bf16(float v, ushort& h, ushort& l) {
    __hip_bfloat16 hb = __float2bfloat16(v);
    float hf = __bfloat162float(hb);
    __hip_bfloat16 lb = __float2bfloat16(v - hf);
    h = *reinterpret_cast<ushort*>(&hb);
    l = *reinterpret_cast<ushort*>(&lb);
}

__device__ __forceinline__ void gl_lds16(const void* g, const void* lds_uniform_base) {
    __builtin_amdgcn_global_load_lds(
        (const __attribute__((address_space(1))) void*)g,
        (__attribute__((address_space(3))) void*)lds_uniform_base,
        16, 0, 0);
}

__device__ __forceinline__ int sigr(int r) { return r ^ ((r >> 3) & 7); }

// ------------------------------- conv1b ------------------------------------
__global__ __launch_bounds__(256) void conv1b_kernel(
    const float* __restrict__ img, const float* __restrict__ w,
    const float* __restrict__ bias, ushort* __restrict__ xH0, ushort* __restrict__ xL0)
{
    const int ct = blockIdx.x;
    const int b  = blockIdx.y;
    const int t  = threadIdx.x;
    __shared__ float img_s[784];
    __shared__ float w_s[64 * 81];
    for (int idx = t; idx < 784; idx += 256) img_s[idx] = img[b * 784 + idx];
    for (int idx = t; idx < 64 * 81; idx += 256) w_s[idx] = w[ct * 64 * 81 + idx];
    __syncthreads();
    for (int task = t; task < 1280; task += 256) {
        const int cl = task / 20;
        const int oy = task - cl * 20;
        float acc[20];
        const float bv = bias[ct * 64 + cl];
#pragma unroll
        for (int j = 0; j < 20; ++j) acc[j] = bv;
#pragma unroll
        for (int ky = 0; ky < 9; ++ky) {
            float rowv[28];
            const float* r = &img_s[(oy + ky) * 28];
#pragma unroll
            for (int j = 0; j < 28; ++j) rowv[j] = r[j];
#pragma unroll
            for (int kx = 0; kx < 9; ++kx) {
                const float wv = w_s[cl * 81 + ky * 9 + kx];
#pragma unroll
                for (int j = 0; j < 20; ++j) acc[j] += wv * rowv[j + kx];
            }
        }
        const size_t row = ((size_t)b * 256 + ct * 64 + cl) * 400 + oy * 20;
        uint* ph = (uint*)(xH0 + row);
        uint* pl = (uint*)(xL0 + row);
#pragma unroll
        for (int j = 0; j < 10; ++j) {
            ushort h0, l0, h1, l1;
            split_bf16(fmaxf(acc[2 * j], 0.f), h0, l0);
            split_bf16(fmaxf(acc[2 * j + 1], 0.f), h1, l1);
            ph[j] = (uint)h0 | ((uint)h1 << 16);
            pl[j] = (uint)l0 | ((uint)l1 << 16);
        }
    }
}

// ------------------------------ xsplit3 ------------------------------------
__global__ __launch_bounds__(256) void xsplit3_kernel(
    const ushort* __restrict__ xH0, const ushort* __restrict__ xL0,
    ushort* __restrict__ xTh, ushort* __restrict__ xTl)
{
    const int b   = blockIdx.x;   // 128
    const int icb = blockIdx.y;   // 8 (32 ic each = 4 cc chunks)
    const int t   = threadIdx.x;
    __shared__ ushort xs[32 * 408];
#pragma unroll
    for (int pol = 0; pol < 2; ++pol) {
        const ushort* src = pol ? xL0 : xH0;
        ushort* dst = pol ? xTl : xTh;
        if (pol) __syncthreads();
        for (int idx = t; idx < 12800; idx += 256) {
            const int ic = idx / 400;
            const int p  = idx - ic * 400;
            xs[ic * 408 + p] = src[((size_t)b * 256 + icb * 32 + ic) * 400 + p];
        }
        __syncthreads();
        for (int u = t; u < 1600; u += 256) {
            const int c = u / 400;
            const int p = u - c * 400;
            ushort8v v;
#pragma unroll
            for (int j = 0; j < 8; ++j) v[j] = xs[(c * 8 + j) * 408 + p];
            const int cc = icb * 4 + c;
            *(ushort8v*)(dst + (((size_t)b * 32 + cc) * 400 + p) * 8) = v;
        }
    }
}

// ------------------------------ wsplit2 ------------------------------------
__global__ __launch_bounds__(256) void wsplit2_kernel(
    const float* __restrict__ pw, ushort* __restrict__ Wfh, ushort* __restrict__ Wfl)
{
    const int oc = blockIdx.x;    // 256
    const int t  = threadIdx.x;
    __shared__ float buf[648];
    const float* row = pw + (size_t)oc * 20736;
    for (int qc = 0; qc < 32; ++qc) {
        __syncthreads();
        for (int idx = t; idx < 648; idx += 256) buf[idx] = row[qc * 648 + idx];
        __syncthreads();
        if (t < 82) {
            const int T  = t >> 1;
            const int hh = t & 1;
            const int tap = 2 * T + hh;
            ushort8v h8, l8;
#pragma unroll
            for (int j = 0; j < 8; ++j) {
                const float v = (tap <= 80) ? buf[j * 81 + tap] : 0.f;
                ushort hb, lb;
                split_bf16(v, hb, lb);
                h8[j] = hb; l8[j] = lb;
            }
            const size_t rec = (((size_t)(qc * 41 + T) * 256 + oc) * 2 + hh) * 8;
            *(ushort8v*)(Wfh + rec) = h8;
            *(ushort8v*)(Wfl + rec) = l8;
        }
    }
}

// ------------------------------- gemm9 -------------------------------------
__global__ __launch_bounds__(256, 3) void gemm9_kernel(
    const ushort* __restrict__ xTh, const ushort* __restrict__ xTl,
    const ushort* __restrict__ Wfh, const ushort* __restrict__ Wfl,
    float* __restrict__ part)
{
    const int bid = blockIdx.x;          // 576
    const int q = bid & 7, mt = bid >> 3;
    const int t = threadIdx.x;           // 0..255
    const int w = t >> 6, lane = t & 63; // w = og (0..3)
    const int ln = lane & 31, h = lane >> 5;

    __shared__ ushort As[20480];         // 40,960 B: hi slots [0,1200), lo base 1280

    const int m_base = mt * 64;
    const int bmin = m_base / 36;

    // staging source byte offsets: 5 rounds of 256 slots (last partial, t<176)
    uint soff[5];
#pragma unroll
    for (int r = 0; r < 5; ++r) {
        int j = t + r * 256;
        if (j >= 1200) j = 0;
        const int rbj = j / 400;
        const int gp  = sigr(j) - rbj * 400;   // sigma stays in 400-block (400%8==0)
        soff[r] = (uint)((bmin + rbj) * 204800 + q * 25600 + gp * 16);
    }

    int pb0, pb1;
    {
        int m = m_base + ln;
        int b = m / 36, pos = m - b * 36;
        pb0 = (b - bmin) * 400 + (pos / 6) * 40 + (pos % 6) * 2;
        m += 32;
        b = m / 36; pos = m - b * 36;
        pb1 = (b - bmin) * 400 + (pos / 6) * 40 + (pos % 6) * 2;
    }

    const uint wlane = (uint)((w * 64 + ln) * 16 + h * 8);

    f32x16 acc00, acc01, acc10, acc11;
#pragma unroll
    for (int i = 0; i < 16; ++i) { acc00[i] = 0.f; acc01[i] = 0.f; acc10[i] = 0.f; acc11[i] = 0.f; }

#define G9_STAGE(c_)                                                           \
    {                                                                          \
        const uint cc = (uint)(c_) * 6400u;                                    \
        _Pragma("unroll")                                                      \
        for (int r = 0; r < 5; ++r) {                                          \
            if (r < 4 || t < 176) {                                            \
                gl_lds16((const char*)xTh + soff[r] + cc,                      \
                         (char*)As + (r * 256 + w * 64) * 16);                 \
                gl_lds16((const char*)xTl + soff[r] + cc,                      \
                         (char*)As + 20480 + (r * 256 + w * 64) * 16);         \
            }                                                                  \
        }                                                                      \
    }

    for (int c = 0; c < 4; ++c) {
        if (c > 0) __syncthreads();     // previous icchunk's readers done
        G9_STAGE(c);
        __syncthreads();                // implicit vmcnt(0): stage visible

        const ushort* wph = Wfh + (size_t)(q * 4 + c) * 41 * 4096 + wlane;
        const ushort* wpl = Wfl + (size_t)(q * 4 + c) * 41 * 4096 + wlane;
        short8 cw0h = *(const short8*)(wph);
        short8 cw1h = *(const short8*)(wph + 512);    // +32 oc (oc stride 16)
        short8 cw0l = *(const short8*)(wpl);
        short8 cw1l = *(const short8*)(wpl + 512);

        int off = h;                    // tap 0 for this lane half: ky0=0, kx0=h
        int kxc = h;
        int s0 = sigr(pb0 + off), s1 = sigr(pb1 + off);
        short8 ca0h = *(const short8*)(As + s0 * 8);
        short8 ca0l = *(const short8*)(As + (1280 + s0) * 8);
        short8 ca1h = *(const short8*)(As + s1 * 8);
        short8 ca1l = *(const short8*)(As + (1280 + s1) * 8);

        for (int T = 0; T < 41; ++T) {
            const int  step = (T < 40) ? 4096 : 0;
            const bool wrap = (kxc >= 7);
            const int  offn = (T < 40) ? (off + (wrap ? 13 : 2)) : off;
            const int  kxn  = (T < 40) ? (kxc + (wrap ? -7 : 2)) : kxc;
            const int  t0 = sigr(pb0 + offn), t1 = sigr(pb1 + offn);
            // prefetch next A (LDS) and next W (L2) while MFMAs run
            const short8 na0h = *(const short8*)(As + t0 * 8);
            const short8 na0l = *(const short8*)(As + (1280 + t0) * 8);
            const short8 na1h = *(const short8*)(As + t1 * 8);
            const short8 na1l = *(const short8*)(As + (1280 + t1) * 8);
            const short8 nw0h = *(const short8*)(wph + step);
            const short8 nw1h = *(const short8*)(wph + step + 512);
            const short8 nw0l = *(const short8*)(wpl + step);
            const short8 nw1l = *(const short8*)(wpl + step + 512);
            acc00 = MFMA32(ca0h, cw0h, acc00);
            acc00 = MFMA32(ca0l, cw0h, acc00);
            acc00 = MFMA32(ca0h, cw0l, acc00);
            acc01 = MFMA32(ca0h, cw1h, acc01);
            acc01 = MFMA32(ca0l, cw1h, acc01);
            acc01 = MFMA32(ca0h, cw1l, acc01);
            acc10 = MFMA32(ca1h, cw0h, acc10);
            acc10 = MFMA32(ca1l, cw0h, acc10);
            acc10 = MFMA32(ca1h, cw0l, acc10);
            acc11 = MFMA32(ca1h, cw1h, acc11);
            acc11 = MFMA32(ca1l, cw1h, acc11);
            acc11 = MFMA32(ca1h, cw1l, acc11);
            ca0h = na0h; ca0l = na0l; ca1h = na1h; ca1l = na1l;
            cw0h = nw0h; cw1h = nw1h; cw0l = nw0l; cw1l = nw1l;
            wph += step; wpl += step;
            off = offn; kxc = kxn;
        }
    }
#undef G9_STAGE

    // epilogue: C[m][oc] -> part[q][b][cap][pos][d]
    float* pq = part + (size_t)q * 1179648;
#pragma unroll
    for (int mf = 0; mf < 2; ++mf) {
#pragma unroll
        for (int nf = 0; nf < 2; ++nf) {
            const f32x16 a = (mf == 0) ? (nf == 0 ? acc00 : acc01)
                                       : (nf == 0 ? acc10 : acc11);
            const int oc = w * 64 + nf * 32 + ln;
            float* pb = pq + (oc >> 3) * 288 + (oc & 7);
#pragma unroll
            for (int r = 0; r < 16; ++r) {
                const int m = m_base + mf * 32 + (r & 3) + 8 * (r >> 2) + 4 * h;
                const int b = m / 36;
                const int pos = m - b * 36;
                pb[(size_t)b * 9216 + pos * 8] = a[r];
            }
        }
    }
}

// ------------------------------- squash ------------------------------------
__global__ __launch_bounds__(256) void squash_kernel(
    const float* __restrict__ part, const float* __restrict__ bias,
    float* __restrict__ u, int nq)
{
    const int idx = blockIdx.x * 256 + threadIdx.x;
    if (idx >= 128 * 1152) return;
    const int i   = idx % 1152;
    const int cap = i / 36;
    float v[8];
    float n2 = 0.f;
#pragma unroll
    for (int c = 0; c < 8; ++c) {
        float s = bias[cap * 8 + c];
        for (int qq = 0; qq < nq; ++qq) s += part[(size_t)qq * 1179648 + (size_t)idx * 8 + c];
        v[c] = s;
        n2 += s * s;
    }
    const float sc = sqrtf(n2) / (1.f + n2);
#pragma unroll
    for (int c = 0; c < 8; ++c) u[(size_t)idx * 8 + c] = v[c] * sc;
}

// ------------------------------- routing v2 --------------------------------
__device__ __forceinline__ float4 uhat4(const float* __restrict__ urow,
                                        const float* __restrict__ wrow)
{
    float ur[8];
    const float4 u0 = *(const float4*)urow;
    const float4 u1 = *(const float4*)(urow + 4);
    ur[0] = u0.x; ur[1] = u0.y; ur[2] = u0.z; ur[3] = u0.w;
    ur[4] = u1.x; ur[5] = u1.y; ur[6] = u1.z; ur[7] = u1.w;
    float4 uh = make_float4(0.f, 0.f, 0.f, 0.f);
#pragma unroll
    for (int c = 0; c < 8; ++c) {
        const float4 wv = *(const float4*)(wrow + c * 16);
        uh.x += ur[c] * wv.x; uh.y += ur[c] * wv.y;
        uh.z += ur[c] * wv.z; uh.w += ur[c] * wv.w;
    }
    return uh;
}

__device__ __forceinline__ float4 uh_from_lds(const ushort* uhs, int i, int d4)
{
    const uint2 rv = *(const uint2*)(uhs + i * 16 + d4);
    float4 r;
    r.x = __uint_as_float((rv.x & 0xffffu) << 16);
    r.y = __uint_as_float((rv.x >> 16) << 16);
    r.z = __uint_as_float((rv.y & 0xffffu) << 16);
    r.w = __uint_as_float((rv.y >> 16) << 16);
    return r;
}

__global__ __launch_bounds__(256) void routing_kernel(
    const float* __restrict__ u, const float* __restrict__ rw,
    float* __restrict__ out)
{
    const int b = blockIdx.x;
    const int o = blockIdx.y;
    const int t = threadIdx.x;
    __shared__ ushort uh_s[1152 * 16];
    __shared__ float logits[1152];
    __shared__ float ebuf[1152];
    __shared__ float psum[64][17];
    __shared__ float red[8];
    __shared__ float v_s[16];
    const float* ub = u + (size_t)b * 9216;
    const float* wo = rw + (size_t)o * 147456;
    for (int i = t; i < 1152; i += 256) logits[i] = 0.f;
    __syncthreads();
    const int dq = t & 3;
    const int ig = t >> 2;
    const int d4 = dq * 4;
    for (int iter = 1; iter <= 3; ++iter) {
        float lmax = -3.0e38f;
        for (int i = t; i < 1152; i += 256) lmax = fmaxf(lmax, logits[i]);
#pragma unroll
        for (int off = 32; off; off >>= 1) lmax = fmaxf(lmax, __shfl_xor(lmax, off, 64));
        if ((t & 63) == 0) red[t >> 6] = lmax;
        __syncthreads();
        const float m = fmaxf(fmaxf(red[0], red[1]), fmaxf(red[2], red[3]));
        float ls = 0.f;
        for (int i = t; i < 1152; i += 256) {
            const float e = expf(logits[i] - m);
            ebuf[i] = e;
            ls += e;
        }
#pragma unroll
        for (int off = 32; off; off >>= 1) ls += __shfl_xor(ls, off, 64);
        if ((t & 63) == 0) red[4 + (t >> 6)] = ls;
        __syncthreads();
        const float sumE = red[4] + red[5] + red[6] + red[7];
        float4 ps = make_float4(0.f, 0.f, 0.f, 0.f);
        if (iter == 1) {
            for (int i = ig; i < 1152; i += 64) {
                const float4 uh = uhat4(ub + i * 8, wo + (size_t)i * 128 + d4);
                ushort4 hb;
                __hip_bfloat16 q0 = __float2bfloat16(uh.x);
                __hip_bfloat16 q1 = __float2bfloat16(uh.y);
                __hip_bfloat16 q2 = __float2bfloat16(uh.z);
                __hip_bfloat16 q3 = __float2bfloat16(uh.w);
                hb.x = *(ushort*)&q0; hb.y = *(ushort*)&q1;
                hb.z = *(ushort*)&q2; hb.w = *(ushort*)&q3;
                *(ushort4*)(uh_s + i * 16 + d4) = hb;
                const float e = ebuf[i];
                ps.x += e * uh.x; ps.y += e * uh.y; ps.z += e * uh.z; ps.w += e * uh.w;
            }
        } else {
            for (int i = ig; i < 1152; i += 64) {
                const float4 uh = uh_from_lds(uh_s, i, d4);
                const float e = ebuf[i];
                ps.x += e * uh.x; ps.y += e * uh.y; ps.z += e * uh.z; ps.w += e * uh.w;
            }
        }
        psum[ig][d4 + 0] = ps.x; psum[ig][d4 + 1] = ps.y;
        psum[ig][d4 + 2] = ps.z; psum[ig][d4 + 3] = ps.w;
        __syncthreads();
        if (t < 16) {
            float s = 0.f;
            for (int g = 0; g < 64; ++g) s += psum[g][t];
            s /= sumE;
            float qn = s * s;
            qn += __shfl_xor(qn, 1, 16); qn += __shfl_xor(qn, 2, 16);
            qn += __shfl_xor(qn, 4, 16); qn += __shfl_xor(qn, 8, 16);
            v_s[t] = s * sqrtf(qn) / (1.f + qn);
        }
        __syncthreads();
        if (iter < 3) {
            const float v0 = v_s[d4 + 0], v1 = v_s[d4 + 1];
            const float v2 = v_s[d4 + 2], v3 = v_s[d4 + 3];
            for (int i = ig; i < 1152; i += 64) {
                const float4 uh = uh_from_lds(uh_s, i, d4);
                float pr = uh.x * v0 + uh.y * v1 + uh.z * v2 + uh.w * v3;
                pr += __shfl_xor(pr, 1, 64);
                pr += __shfl_xor(pr, 2, 64);
                if (dq == 0) logits[i] += pr;
            }
            __syncthreads();
        }
    }
    if (t < 16) out[((size_t)b * 10 + o) * 16 + t] = v_s[t];
}

// ===================== FALLBACK (R5 fp32 direct conv) ======================
#define WSL4 1344

__global__ __launch_bounds__(256) void conv1_kernel(
    const float* __restrict__ img, const float* __restrict__ w,
    const float* __restrict__ bias, float* __restrict__ x)
{
    const int ct = blockIdx.x;
    const int b  = blockIdx.y;
    const int t  = threadIdx.x;
    __shared__ float img_s[784];
    __shared__ float w_s[64 * 81];
    for (int idx = t; idx < 784; idx += 256) img_s[idx] = img[b * 784 + idx];
    for (int idx = t; idx < 64 * 81; idx += 256) w_s[idx] = w[ct * 64 * 81 + idx];
    __syncthreads();
    for (int task = t; task < 1280; task += 256) {
        const int cl = task / 20;
        const int oy = task - cl * 20;
        float acc[20];
        const float bv = bias[ct * 64 + cl];
#pragma unroll
        for (int j = 0; j < 20; ++j) acc[j] = bv;
#pragma unroll
        for (int ky = 0; ky < 9; ++ky) {
            float rowv[28];
            const float* r = &img_s[(oy + ky) * 28];
#pragma unroll
            for (int j = 0; j < 28; ++j) rowv[j] = r[j];
#pragma unroll
            for (int kx = 0; kx < 9; ++kx) {
                const float wv = w_s[cl * 81 + ky * 9 + kx];
#pragma unroll
                for (int j = 0; j < 20; ++j) acc[j] += wv * rowv[j + kx];
            }
        }
        float* xp = x + (((size_t)b * 256 + ct * 64 + cl) * 400) + oy * 20;
#pragma unroll
        for (int j = 0; j < 20; ++j) xp[j] = fmaxf(acc[j], 0.f);
    }
}

__global__ __launch_bounds__(256) void wtrans_kernel(
    const float* __restrict__ w, float* __restrict__ wT)
{
    const int idx = blockIdx.x * 256 + threadIdx.x;
    if (idx >= 4 * 256 * 81 * 16) return;
    const int c      = idx & 15;
    const int k      = (idx >> 4) % 81;
    const int ic     = ((idx >> 4) / 81) % 256;
    const int octile = idx / (16 * 81 * 256);
    const int ocb    = octile * 64 + c * 4;
    float4 v;
    v.x = w[((size_t)(ocb + 0) * 256 + ic) * 81 + k];
    v.y = w[((size_t)(ocb + 1) * 256 + ic) * 81 + k];
    v.z = w[((size_t)(ocb + 2) * 256 + ic) * 81 + k];
    v.w = w[((size_t)(ocb + 3) * 256 + ic) * 81 + k];
    ((float4*)wT)[((size_t)octile * 256 + ic) * WSL4 + k * 16 + c] = v;
}

__global__ __launch_bounds__(384) void pcaps_kernel(
    const float* __restrict__ x, const float* __restrict__ wT,
    float* __restrict__ part)
{
    const int btile  = blockIdx.x;
    const int octile = blockIdx.y;
    const int ict    = blockIdx.z;
    const int t    = threadIdx.x;
    const int wave = t >> 6;
    const int lane = t & 63;
    __shared__ float4 w_s[2][WSL4];
    __shared__ float4 x_s[2][448];
    const int oc4  = (t & 15) * 4;
    const int slot = t >> 4;
    const int bb   = slot / 6;
    const int oy   = slot - 6 * bb;
    const int b0   = btile * 4;
    float acc[6][4];
#pragma unroll
    for (int p = 0; p < 6; ++p) {
        acc[p][0] = 0.f; acc[p][1] = 0.f; acc[p][2] = 0.f; acc[p][3] = 0.f;
    }
    const float*  xg   = x + (size_t)b0 * 102400 + (size_t)ict * 25600;
    const float4* wsrc = (const float4*)wT + ((size_t)octile * 256 + ict * 64) * WSL4;
#define PCAPS_STAGE(bf_, ic_)                                                  \
    {                                                                          \
        const float4* gsl = wsrc + (size_t)(ic_) * WSL4;                       \
        for (int ch = wave; ch < 21; ch += 6)                                  \
            gl_lds16(gsl + ch * 64 + lane, &w_s[bf_][ch * 64]);                \
        for (int ch = wave; ch < 7; ch += 6) {                                 \
            int idx = ch * 64 + lane;                                          \
            if (idx >= 400) idx = 0;                                           \
            const int xbb = idx / 100;                                         \
            const int off = idx - xbb * 100;                                   \
            const float* g = xg + (size_t)xbb * 102400 + (ic_) * 400 + off * 4;\
            gl_lds16(g, &x_s[bf_][ch * 64]);                                   \
        }                                                                      \
    }
    PCAPS_STAGE(0, 0);
    __syncthreads();
    int buf = 0;
    for (int ic = 0; ic < 64; ++ic) {
        if (ic < 63) PCAPS_STAGE(buf ^ 1, ic + 1);
        const float* xrow = (const float*)x_s[buf] + bb * 400;
        const float* wrow = (const float*)w_s[buf];
#pragma unroll
        for (int ky = 0; ky < 9; ++ky) {
            float rowv[20];
            const float4* xr = (const float4*)&xrow[(2 * oy + ky) * 20];
#pragma unroll
            for (int j = 0; j < 5; ++j) ((float4*)rowv)[j] = xr[j];
#pragma unroll
            for (int kx = 0; kx < 9; ++kx) {
                const float4 wv = *(const float4*)&wrow[(ky * 9 + kx) * 64 + oc4];
#pragma unroll
                for (int p = 0; p < 6; ++p) {
                    const float xv = rowv[2 * p + kx];
                    acc[p][0] += xv * wv.x; acc[p][1] += xv * wv.y;
                    acc[p][2] += xv * wv.z; acc[p][3] += xv * wv.w;
                }
            }
        }
        __syncthreads();
        buf ^= 1;
    }
#undef PCAPS_STAGE
    float* pb = part + ((size_t)ict * 128 + (b0 + bb)) * 9216;
    const int oc0 = octile * 64 + oc4;
    const int cap = oc0 >> 3;
    const int d0  = oc0 & 7;
#pragma unroll
    for (int p = 0; p < 6; ++p) {
        const int pos = oy * 6 + p;
        *(float4*)&pb[((size_t)cap * 36 + pos) * 8 + d0] =
            make_float4(acc[p][0], acc[p][1], acc[p][2], acc[p][3]);
    }
}

// ------------------------------- launcher ----------------------------------
extern "C" void kernel_launch(void* const* d_in, const int* in_sizes, int n_in,
                              void* d_out, int out_size, void* d_ws, size_t ws_size,
                              hipStream_t stream)
{
    const float* img = (const float*)d_in[0];
    const float* c1w = (const float*)d_in[1];
    const float* c1b = (const float*)d_in[2];
    const float* pw  = (const float*)d_in[3];
    const float* pb  = (const float*)d_in[4];
    const float* rw  = (const float*)d_in[5];
    float* out = (float*)d_out;
    char* ws = (char*)d_ws;

    if (ws_size >= 116391936ULL) {
        // fast path (116,391,936 B) — lifetime map in header comment.
        ushort* xTh  = (ushort*)(ws);                  // [0, 26,214,400)
        ushort* xTl  = (ushort*)(ws + 26214400);       // [26,214,400, 52,428,800)
        ushort* xH0  = (ushort*)(ws + 52428800);       // dead after xsplit3
        ushort* xL0  = (ushort*)(ws + 78643200);       // dead after xsplit3
        ushort* Wfh  = (ushort*)(ws + 52428800);       // aliases dead xH0
        ushort* Wfl  = (ushort*)(ws + 63176704);
        float*  part = (float*)(ws + 73924608);        // aliases dead xL0
        float*  u    = (float*)(ws + 111673344);
        hipLaunchKernelGGL(conv1b_kernel, dim3(4, 128), dim3(256), 0, stream, img, c1w, c1b, xH0, xL0);
        hipLaunchKernelGGL(xsplit3_kernel, dim3(128, 8), dim3(256), 0, stream, xH0, xL0, xTh, xTl);
        hipLaunchKernelGGL(wsplit2_kernel, dim3(256), dim3(256), 0, stream, pw, Wfh, Wfl);   // after xsplit3!
        hipLaunchKernelGGL(gemm9_kernel, dim3(576), dim3(256), 0, stream, xTh, xTl, Wfh, Wfl, part);
        hipLaunchKernelGGL(squash_kernel, dim3(576), dim3(256), 0, stream, part, pb, u, 8);
        hipLaunchKernelGGL(routing_kernel, dim3(128, 10), dim3(256), 0, stream, u, rw, out);
    } else {
        // fallback: R5 fp32 direct conv (97.9 MB, proven)
        float* x    = (float*)(ws);
        float* part = (float*)(ws + 52428800);
        float* u    = (float*)(ws + 52428800 + 18874368);
        float* wT   = (float*)(ws + 52428800 + 18874368 + 4718592);
        hipLaunchKernelGGL(wtrans_kernel, dim3((4 * 256 * 81 * 16 + 255) / 256), dim3(256), 0, stream, pw, wT);
        hipLaunchKernelGGL(conv1_kernel, dim3(4, 128), dim3(256), 0, stream, img, c1w, c1b, x);
        hipLaunchKernelGGL(pcaps_kernel, dim3(32, 4, 4), dim3(384), 0, stream, x, wT, part);
        hipLaunchKernelGGL(squash_kernel, dim3(576), dim3(256), 0, stream, part, pb, u, 4);
        hipLaunchKernelGGL(routing_kernel, dim3(128, 10), dim3(256), 0, stream, u, rw, out);
    }
}

// Round 17
// 271.745 us; speedup vs baseline: 1.2987x; 1.2087x over previous
//
#include <hip/hip_runtime.h>
#include <hip/hip_bf16.h>
#include <math.h>

// ---------------------------------------------------------------------------
// CapsuleNetwork forward.
// FAST PATH (ws >= 116,391,936 B):
//   conv1c : img -> xTh/xTl [128 b][32 cc][400 pos][8 ic] bf16 hi/lo DIRECTLY
//            (conv + split + transpose fused via LDS, two 32-channel phases)
//   wsplit3: pcaps_w -> Wf hi/lo [qc=32][T=41][256 oc][2 h][8 ic], tap=2T+h
//            (1024 blocks = 256 oc x 4 qc-groups)
//   gemm9  : 576 blocks = 72 mt(64 rows) x 8 q(32-ic group), 4 waves (64 oc),
//            A staged per icchunk (sigma swizzle), reg-dbuf A+W, 12 MFMA/T.
//   squash : part(nq=8)+bias -> u (float4 accumulate)
//   uhat   : u, rw -> uh bf16 [b][o][1152][16]  (rw read ONCE; grid i-chunk x o)
//   routing: uh slice -> LDS, 3 dynamic-routing iters -> out
// Workspace: xTh [0,26.2M) xTl [26.2,52.4M) (dead after gemm9; uh aliases [0,47.2M))
//            Wfh [52.4,63.2M) Wfl [63.2,73.9M); part [73.9,111.7M); u [111.7,116.4M)
// FALLBACK: R5 fp32 direct-conv path.
// ---------------------------------------------------------------------------

typedef __attribute__((ext_vector_type(8)))  short  short8;
typedef __attribute__((ext_vector_type(8)))  ushort ushort8v;
typedef __attribute__((ext_vector_type(16))) float  f32x16;
#define MFMA32(a, b, c) __builtin_amdgcn_mfma_f32_32x32x16_bf16(a, b, c, 0, 0, 0)

__device__ __forceinline__ void split_bf16(float v, ushort& h, ushort& l) {
    __hip_bfloat16 hb = __float2bfloat16(v);
    float hf = __bfloat162float(hb);
    __hip_bfloat16 lb = __float2bfloat16(v - hf);
    h = *reinterpret_cast<ushort*>(&hb);
    l = *reinterpret_cast<ushort*>(&lb);
}

__device__ __forceinline__ void gl_lds16(const void* g, const void* lds_uniform_base) {
    __builtin_amdgcn_global_load_lds(
        (const __attribute__((address_space(1))) void*)g,
        (__attribute__((address_space(3))) void*)lds_uniform_base,
        16, 0, 0);
}

__device__ __forceinline__ int sigr(int r) { return r ^ ((r >> 3) & 7); }

// ------------------------------- conv1c ------------------------------------
// conv1 + relu + bf16 hi/lo split + channel-last transpose, all in one.
__global__ __launch_bounds__(256) void conv1c_kernel(
    const float* __restrict__ img, const float* __restrict__ w,
    const float* __restrict__ bias, ushort* __restrict__ xTh, ushort* __restrict__ xTl)
{
    const int ct = blockIdx.x;   // 4 (64-channel tile)
    const int b  = blockIdx.y;   // 128
    const int t  = threadIdx.x;
    __shared__ float img_s[784];
    __shared__ float w_s[64 * 81];
    __shared__ ushort xsH[32][408];
    __shared__ ushort xsL[32][408];
    for (int idx = t; idx < 784; idx += 256) img_s[idx] = img[b * 784 + idx];
    for (int idx = t; idx < 64 * 81; idx += 256) w_s[idx] = w[ct * 64 * 81 + idx];
    __syncthreads();
#pragma unroll
    for (int ph = 0; ph < 2; ++ph) {     // two 32-channel phases
        if (ph) __syncthreads();         // xs reuse safe
        for (int task = t; task < 640; task += 256) {
            const int cl2 = task / 20;   // 0..31
            const int cl  = ph * 32 + cl2;
            const int oy  = task - cl2 * 20;
            float acc[20];
            const float bv = bias[ct * 64 + cl];
#pragma unroll
            for (int j = 0; j < 20; ++j) acc[j] = bv;
#pragma unroll
            for (int ky = 0; ky < 9; ++ky) {
                float rowv[28];
                const float* r = &img_s[(oy + ky) * 28];
#pragma unroll
                for (int j = 0; j < 28; ++j) rowv[j] = r[j];
#pragma unroll
                for (int kx = 0; kx < 9; ++kx) {
                    const float wv = w_s[cl * 81 + ky * 9 + kx];
#pragma unroll
                    for (int j = 0; j < 20; ++j) acc[j] += wv * rowv[j + kx];
                }
            }
#pragma unroll
            for (int j = 0; j < 20; ++j) {
                ushort hb, lb;
                split_bf16(fmaxf(acc[j], 0.f), hb, lb);
                xsH[cl2][oy * 20 + j] = hb;
                xsL[cl2][oy * 20 + j] = lb;
            }
        }
        __syncthreads();
        for (int u2 = t; u2 < 1600; u2 += 256) {
            const int c = u2 / 400;      // 0..3
            const int p = u2 - c * 400;
            ushort8v vh, vl;
#pragma unroll
            for (int j = 0; j < 8; ++j) {
                vh[j] = xsH[c * 8 + j][p];
                vl[j] = xsL[c * 8 + j][p];
            }
            const int cc = ct * 8 + ph * 4 + c;   // 0..31
            const size_t o = (((size_t)b * 32 + cc) * 400 + p) * 8;
            *(ushort8v*)(xTh + o) = vh;
            *(ushort8v*)(xTl + o) = vl;
        }
    }
}

// ------------------------------ wsplit3 ------------------------------------
__global__ __launch_bounds__(256) void wsplit3_kernel(
    const float* __restrict__ pw, ushort* __restrict__ Wfh, ushort* __restrict__ Wfl)
{
    const int oc = blockIdx.x & 255;
    const int qg = blockIdx.x >> 8;      // 0..3 (8 qc each)
    const int t  = threadIdx.x;
    __shared__ float buf[5184];          // 8 qc x 8 ic x 81 tap
    const float* row = pw + (size_t)oc * 20736 + qg * 5184;
    for (int idx = t; idx < 5184; idx += 256) buf[idx] = row[idx];
    __syncthreads();
    for (int task = t; task < 656; task += 256) {
        const int qcl = task / 82;
        const int tt  = task - qcl * 82;
        const int T   = tt >> 1;
        const int hh  = tt & 1;
        const int tap = 2 * T + hh;
        const int qc  = qg * 8 + qcl;
        ushort8v h8, l8;
#pragma unroll
        for (int j = 0; j < 8; ++j) {
            const float v = (tap <= 80) ? buf[qcl * 648 + j * 81 + tap] : 0.f;
            ushort hb, lb;
            split_bf16(v, hb, lb);
            h8[j] = hb; l8[j] = lb;
        }
        const size_t rec = (((size_t)(qc * 41 + T) * 256 + oc) * 2 + hh) * 8;
        *(ushort8v*)(Wfh + rec) = h8;
        *(ushort8v*)(Wfl + rec) = l8;
    }
}

// ------------------------------- gemm9 (frozen from R16) -------------------
__global__ __launch_bounds__(256, 3) void gemm9_kernel(
    const ushort* __restrict__ xTh, const ushort* __restrict__ xTl,
    const ushort* __restrict__ Wfh, const ushort* __restrict__ Wfl,
    float* __restrict__ part)
{
    const int bid = blockIdx.x;          // 576
    const int q = bid & 7, mt = bid >> 3;
    const int t = threadIdx.x;           // 0..255
    const int w = t >> 6, lane = t & 63; // w = og (0..3)
    const int ln = lane & 31, h = lane >> 5;

    __shared__ ushort As[20480];

    const int m_base = mt * 64;
    const int bmin = m_base / 36;

    uint soff[5];
#pragma unroll
    for (int r = 0; r < 5; ++r) {
        int j = t + r * 256;
        if (j >= 1200) j = 0;
        const int rbj = j / 400;
        const int gp  = sigr(j) - rbj * 400;
        soff[r] = (uint)((bmin + rbj) * 204800 + q * 25600 + gp * 16);
    }

    int pb0, pb1;
    {
        int m = m_base + ln;
        int b = m / 36, pos = m - b * 36;
        pb0 = (b - bmin) * 400 + (pos / 6) * 40 + (pos % 6) * 2;
        m += 32;
        b = m / 36; pos = m - b * 36;
        pb1 = (b - bmin) * 400 + (pos / 6) * 40 + (pos % 6) * 2;
    }

    const uint wlane = (uint)((w * 64 + ln) * 16 + h * 8);

    f32x16 acc00, acc01, acc10, acc11;
#pragma unroll
    for (int i = 0; i < 16; ++i) { acc00[i] = 0.f; acc01[i] = 0.f; acc10[i] = 0.f; acc11[i] = 0.f; }

#define G9_STAGE(c_)                                                           \
    {                                                                          \
        const uint cc = (uint)(c_) * 6400u;                                    \
        _Pragma("unroll")                                                      \
        for (int r = 0; r < 5; ++r) {                                          \
            if (r < 4 || t < 176) {                                            \
                gl_lds16((const char*)xTh + soff[r] + cc,                      \
                         (char*)As + (r * 256 + w * 64) * 16);                 \
                gl_lds16((const char*)xTl + soff[r] + cc,                      \
                         (char*)As + 20480 + (r * 256 + w * 64) * 16);         \
            }                                                                  \
        }                                                                      \
    }

    for (int c = 0; c < 4; ++c) {
        if (c > 0) __syncthreads();
        G9_STAGE(c);
        __syncthreads();

        const ushort* wph = Wfh + (size_t)(q * 4 + c) * 41 * 4096 + wlane;
        const ushort* wpl = Wfl + (size_t)(q * 4 + c) * 41 * 4096 + wlane;
        short8 cw0h = *(const short8*)(wph);
        short8 cw1h = *(const short8*)(wph + 512);
        short8 cw0l = *(const short8*)(wpl);
        short8 cw1l = *(const short8*)(wpl + 512);

        int off = h;
        int kxc = h;
        int s0 = sigr(pb0 + off), s1 = sigr(pb1 + off);
        short8 ca0h = *(const short8*)(As + s0 * 8);
        short8 ca0l = *(const short8*)(As + (1280 + s0) * 8);
        short8 ca1h = *(const short8*)(As + s1 * 8);
        short8 ca1l = *(const short8*)(As + (1280 + s1) * 8);

        for (int T = 0; T < 41; ++T) {
            const int  step = (T < 40) ? 4096 : 0;
            const bool wrap = (kxc >= 7);
            const int  offn = (T < 40) ? (off + (wrap ? 13 : 2)) : off;
            const int  kxn  = (T < 40) ? (kxc + (wrap ? -7 : 2)) : kxc;
            const int  t0 = sigr(pb0 + offn), t1 = sigr(pb1 + offn);
            const short8 na0h = *(const short8*)(As + t0 * 8);
            const short8 na0l = *(const short8*)(As + (1280 + t0) * 8);
            const short8 na1h = *(const short8*)(As + t1 * 8);
            const short8 na1l = *(const short8*)(As + (1280 + t1) * 8);
            const short8 nw0h = *(const short8*)(wph + step);
            const short8 nw1h = *(const short8*)(wph + step + 512);
            const short8 nw0l = *(const short8*)(wpl + step);
            const short8 nw1l = *(const short8*)(wpl + step + 512);
            acc00 = MFMA32(ca0h, cw0h, acc00);
            acc00 = MFMA32(ca0l, cw0h, acc00);
            acc00 = MFMA32(ca0h, cw0l, acc00);
            acc01 = MFMA32(ca0h, cw1h, acc01);
            acc01 = MFMA32(ca0l, cw1h, acc01);
            acc01 = MFMA32(ca0h, cw1l, acc01);
            acc10 = MFMA32(ca1h, cw0h, acc10);
            acc10 = MFMA32(ca1l, cw0h, acc10);
            acc10 = MFMA32(ca1h, cw0l, acc10);
            acc11 = MFMA32(ca1h, cw1h, acc11);
            acc11 = MFMA32(ca1l, cw1h, acc11);
            acc11 = MFMA32(ca1h, cw1l, acc11);
            ca0h = na0h; ca0l = na0l; ca1h = na1h; ca1l = na1l;
            cw0h = nw0h; cw1h = nw1h; cw0l = nw0l; cw1l = nw1l;
            wph += step; wpl += step;
            off = offn; kxc = kxn;
        }
    }
#undef G9_STAGE

    float* pq = part + (size_t)q * 1179648;
#pragma unroll
    for (int mf = 0; mf < 2; ++mf) {
#pragma unroll
        for (int nf = 0; nf < 2; ++nf) {
            const f32x16 a = (mf == 0) ? (nf == 0 ? acc00 : acc01)
                                       : (nf == 0 ? acc10 : acc11);
            const int oc = w * 64 + nf * 32 + ln;
            float* pb = pq + (oc >> 3) * 288 + (oc & 7);
#pragma unroll
            for (int r = 0; r < 16; ++r) {
                const int m = m_base + mf * 32 + (r & 3) + 8 * (r >> 2) + 4 * h;
                const int b = m / 36;
                const int pos = m - b * 36;
                pb[(size_t)b * 9216 + pos * 8] = a[r];
            }
        }
    }
}

// ------------------------------- squash ------------------------------------
__global__ __launch_bounds__(256) void squash_kernel(
    const float* __restrict__ part, const float* __restrict__ bias,
    float* __restrict__ u, int nq)
{
    const int idx = blockIdx.x * 256 + threadIdx.x;
    if (idx >= 128 * 1152) return;
    const int i   = idx % 1152;
    const int cap = i / 36;
    float4 s0 = *(const float4*)(bias + 0) ;  // placeholder; overwritten below
    float4 s1;
    {
        const float* bv = bias + cap * 8;
        s0 = make_float4(bv[0], bv[1], bv[2], bv[3]);
        s1 = make_float4(bv[4], bv[5], bv[6], bv[7]);
    }
    for (int qq = 0; qq < nq; ++qq) {
        const float4* p = (const float4*)(part + (size_t)qq * 1179648 + (size_t)idx * 8);
        const float4 a = p[0], b4 = p[1];
        s0.x += a.x; s0.y += a.y; s0.z += a.z; s0.w += a.w;
        s1.x += b4.x; s1.y += b4.y; s1.z += b4.z; s1.w += b4.w;
    }
    const float n2 = s0.x*s0.x + s0.y*s0.y + s0.z*s0.z + s0.w*s0.w
                   + s1.x*s1.x + s1.y*s1.y + s1.z*s1.z + s1.w*s1.w;
    const float sc = sqrtf(n2) / (1.f + n2);
    float4 o0 = make_float4(s0.x*sc, s0.y*sc, s0.z*sc, s0.w*sc);
    float4 o1 = make_float4(s1.x*sc, s1.y*sc, s1.z*sc, s1.w*sc);
    *(float4*)(u + (size_t)idx * 8)     = o0;
    *(float4*)(u + (size_t)idx * 8 + 4) = o1;
}

// ------------------------------- uhat --------------------------------------
__device__ __forceinline__ float4 uhat4(const float* __restrict__ urow,
                                        const float* __restrict__ wrow)
{
    float ur[8];
    const float4 u0 = *(const float4*)urow;
    const float4 u1 = *(const float4*)(urow + 4);
    ur[0] = u0.x; ur[1] = u0.y; ur[2] = u0.z; ur[3] = u0.w;
    ur[4] = u1.x; ur[5] = u1.y; ur[6] = u1.z; ur[7] = u1.w;
    float4 uh = make_float4(0.f, 0.f, 0.f, 0.f);
#pragma unroll
    for (int c = 0; c < 8; ++c) {
        const float4 wv = *(const float4*)(wrow + c * 16);
        uh.x += ur[c] * wv.x; uh.y += ur[c] * wv.y;
        uh.z += ur[c] * wv.z; uh.w += ur[c] * wv.w;
    }
    return uh;
}

// uh[b][o][i][16] bf16 = sum_c u[b,i,c] * rw[o,i,c,d]; rw read exactly once.
__global__ __launch_bounds__(256) void uhat_kernel(
    const float* __restrict__ u, const float* __restrict__ rw,
    ushort* __restrict__ uh)
{
    const int i0 = blockIdx.x * 16;   // 72 chunks
    const int o  = blockIdx.y;        // 10
    const int t  = threadIdx.x;
    __shared__ float rs[2048];        // [16 i][8 c][16 d]
    const float* rsl = rw + ((size_t)o * 1152 + i0) * 128;
    for (int idx = t; idx < 2048; idx += 256) rs[idx] = rsl[idx];
    __syncthreads();
    const int dq = t & 3, il = (t >> 2) & 15, b0 = t >> 6;
    for (int b = b0; b < 128; b += 4) {
        const float4 v = uhat4(u + ((size_t)b * 1152 + i0 + il) * 8,
                               &rs[il * 128 + dq * 4]);
        __hip_bfloat16 q0 = __float2bfloat16(v.x);
        __hip_bfloat16 q1 = __float2bfloat16(v.y);
        __hip_bfloat16 q2 = __float2bfloat16(v.z);
        __hip_bfloat16 q3 = __float2bfloat16(v.w);
        ushort4 hb;
        hb.x = *(ushort*)&q0; hb.y = *(ushort*)&q1;
        hb.z = *(ushort*)&q2; hb.w = *(ushort*)&q3;
        *(ushort4*)(uh + (((size_t)b * 10 + o) * 1152 + i0 + il) * 16 + dq * 4) = hb;
    }
}

// ------------------------------- routing v3 --------------------------------
__device__ __forceinline__ float4 uh_from_lds(const ushort* uhs, int i, int d4)
{
    const uint2 rv = *(const uint2*)(uhs + i * 16 + d4);
    float4 r;
    r.x = __uint_as_float((rv.x & 0xffffu) << 16);
    r.y = __uint_as_float((rv.x >> 16) << 16);
    r.z = __uint_as_float((rv.y & 0xffffu) << 16);
    r.w = __uint_as_float((rv.y >> 16) << 16);
    return r;
}

__global__ __launch_bounds__(256) void routing_kernel(
    const ushort* __restrict__ uh_g, float* __restrict__ out)
{
    const int b = blockIdx.x;
    const int o = blockIdx.y;
    const int t = threadIdx.x;
    __shared__ ushort uh_s[1152 * 16];
    __shared__ float logits[1152];
    __shared__ float ebuf[1152];
    __shared__ float psum[64][17];
    __shared__ float red[8];
    __shared__ float v_s[16];
    // load u_hat slice (36,864 B) from global, coalesced
    const ushort8v* src = (const ushort8v*)(uh_g + ((size_t)b * 10 + o) * 18432);
    for (int idx = t; idx < 2304; idx += 256) ((ushort8v*)uh_s)[idx] = src[idx];
    for (int i = t; i < 1152; i += 256) logits[i] = 0.f;
    __syncthreads();
    const int dq = t & 3;
    const int ig = t >> 2;
    const int d4 = dq * 4;
    for (int iter = 1; iter <= 3; ++iter) {
        float lmax = -3.0e38f;
        for (int i = t; i < 1152; i += 256) lmax = fmaxf(lmax, logits[i]);
#pragma unroll
        for (int off = 32; off; off >>= 1) lmax = fmaxf(lmax, __shfl_xor(lmax, off, 64));
        if ((t & 63) == 0) red[t >> 6] = lmax;
        __syncthreads();
        const float m = fmaxf(fmaxf(red[0], red[1]), fmaxf(red[2], red[3]));
        float ls = 0.f;
        for (int i = t; i < 1152; i += 256) {
            const float e = expf(logits[i] - m);
            ebuf[i] = e;
            ls += e;
        }
#pragma unroll
        for (int off = 32; off; off >>= 1) ls += __shfl_xor(ls, off, 64);
        if ((t & 63) == 0) red[4 + (t >> 6)] = ls;
        __syncthreads();
        const float sumE = red[4] + red[5] + red[6] + red[7];
        float4 ps = make_float4(0.f, 0.f, 0.f, 0.f);
        for (int i = ig; i < 1152; i += 64) {
            const float4 uhv = uh_from_lds(uh_s, i, d4);
            const float e = ebuf[i];
            ps.x += e * uhv.x; ps.y += e * uhv.y; ps.z += e * uhv.z; ps.w += e * uhv.w;
        }
        psum[ig][d4 + 0] = ps.x; psum[ig][d4 + 1] = ps.y;
        psum[ig][d4 + 2] = ps.z; psum[ig][d4 + 3] = ps.w;
        __syncthreads();
        if (t < 16) {
            float s = 0.f;
            for (int g = 0; g < 64; ++g) s += psum[g][t];
            s /= sumE;
            float qn = s * s;
            qn += __shfl_xor(qn, 1, 16); qn += __shfl_xor(qn, 2, 16);
            qn += __shfl_xor(qn, 4, 16); qn += __shfl_xor(qn, 8, 16);
            v_s[t] = s * sqrtf(qn) / (1.f + qn);
        }
        __syncthreads();
        if (iter < 3) {
            const float v0 = v_s[d4 + 0], v1 = v_s[d4 + 1];
            const float v2 = v_s[d4 + 2], v3 = v_s[d4 + 3];
            for (int i = ig; i < 1152; i += 64) {
                const float4 uhv = uh_from_lds(uh_s, i, d4);
                float pr = uhv.x * v0 + uhv.y * v1 + uhv.z * v2 + uhv.w * v3;
                pr += __shfl_xor(pr, 1, 64);
                pr += __shfl_xor(pr, 2, 64);
                if (dq == 0) logits[i] += pr;
            }
            __syncthreads();
        }
    }
    if (t < 16) out[((size_t)b * 10 + o) * 16 + t] = v_s[t];
}

// ===================== FALLBACK (R5 fp32 direct conv) ======================
#define WSL4 1344

__global__ __launch_bounds__(256) void conv1_kernel(
    const float* __restrict__ img, const float* __restrict__ w,
    const float* __restrict__ bias, float* __restrict__ x)
{
    const int ct = blockIdx.x;
    const int b  = blockIdx.y;
    const int t  = threadIdx.x;
    __shared__ float img_s[784];
    __shared__ float w_s[64 * 81];
    for (int idx = t; idx < 784; idx += 256) img_s[idx] = img[b * 784 + idx];
    for (int idx = t; idx < 64 * 81; idx += 256) w_s[idx] = w[ct * 64 * 81 + idx];
    __syncthreads();
    for (int task = t; task < 1280; task += 256) {
        const int cl = task / 20;
        const int oy = task - cl * 20;
        float acc[20];
        const float bv = bias[ct * 64 + cl];
#pragma unroll
        for (int j = 0; j < 20; ++j) acc[j] = bv;
#pragma unroll
        for (int ky = 0; ky < 9; ++ky) {
            float rowv[28];
            const float* r = &img_s[(oy + ky) * 28];
#pragma unroll
            for (int j = 0; j < 28; ++j) rowv[j] = r[j];
#pragma unroll
            for (int kx = 0; kx < 9; ++kx) {
                const float wv = w_s[cl * 81 + ky * 9 + kx];
#pragma unroll
                for (int j = 0; j < 20; ++j) acc[j] += wv * rowv[j + kx];
            }
        }
        float* xp = x + (((size_t)b * 256 + ct * 64 + cl) * 400) + oy * 20;
#pragma unroll
        for (int j = 0; j < 20; ++j) xp[j] = fmaxf(acc[j], 0.f);
    }
}

__global__ __launch_bounds__(256) void wtrans_kernel(
    const float* __restrict__ w, float* __restrict__ wT)
{
    const int idx = blockIdx.x * 256 + threadIdx.x;
    if (idx >= 4 * 256 * 81 * 16) return;
    const int c      = idx & 15;
    const int k      = (idx >> 4) % 81;
    const int ic     = ((idx >> 4) / 81) % 256;
    const int octile = idx / (16 * 81 * 256);
    const int ocb    = octile * 64 + c * 4;
    float4 v;
    v.x = w[((size_t)(ocb + 0) * 256 + ic) * 81 + k];
    v.y = w[((size_t)(ocb + 1) * 256 + ic) * 81 + k];
    v.z = w[((size_t)(ocb + 2) * 256 + ic) * 81 + k];
    v.w = w[((size_t)(ocb + 3) * 256 + ic) * 81 + k];
    ((float4*)wT)[((size_t)octile * 256 + ic) * WSL4 + k * 16 + c] = v;
}

__global__ __launch_bounds__(384) void pcaps_kernel(
    const float* __restrict__ x, const float* __restrict__ wT,
    float* __restrict__ part)
{
    const int btile  = blockIdx.x;
    const int octile = blockIdx.y;
    const int ict    = blockIdx.z;
    const int t    = threadIdx.x;
    const int wave = t >> 6;
    const int lane = t & 63;
    __shared__ float4 w_s[2][WSL4];
    __shared__ float4 x_s[2][448];
    const int oc4  = (t & 15) * 4;
    const int slot = t >> 4;
    const int bb   = slot / 6;
    const int oy   = slot - 6 * bb;
    const int b0   = btile * 4;
    float acc[6][4];
#pragma unroll
    for (int p = 0; p < 6; ++p) {
        acc[p][0] = 0.f; acc[p][1] = 0.f; acc[p][2] = 0.f; acc[p][3] = 0.f;
    }
    const float*  xg   = x + (size_t)b0 * 102400 + (size_t)ict * 25600;
    const float4* wsrc = (const float4*)wT + ((size_t)octile * 256 + ict * 64) * WSL4;
#define PCAPS_STAGE(bf_, ic_)                                                  \
    {                                                                          \
        const float4* gsl = wsrc + (size_t)(ic_) * WSL4;                       \
        for (int ch = wave; ch < 21; ch += 6)                                  \
            gl_lds16(gsl + ch * 64 + lane, &w_s[bf_][ch * 64]);                \
        for (int ch = wave; ch < 7; ch += 6) {                                 \
            int idx = ch * 64 + lane;                                          \
            if (idx >= 400) idx = 0;                                           \
            const int xbb = idx / 100;                                         \
            const int off = idx - xbb * 100;                                   \
            const float* g = xg + (size_t)xbb * 102400 + (ic_) * 400 + off * 4;\
            gl_lds16(g, &x_s[bf_][ch * 64]);                                   \
        }                                                                      \
    }
    PCAPS_STAGE(0, 0);
    __syncthreads();
    int buf = 0;
    for (int ic = 0; ic < 64; ++ic) {
        if (ic < 63) PCAPS_STAGE(buf ^ 1, ic + 1);
        const float* xrow = (const float*)x_s[buf] + bb * 400;
        const float* wrow = (const float*)w_s[buf];
#pragma unroll
        for (int ky = 0; ky < 9; ++ky) {
            float rowv[20];
            const float4* xr = (const float4*)&xrow[(2 * oy + ky) * 20];
#pragma unroll
            for (int j = 0; j < 5; ++j) ((float4*)rowv)[j] = xr[j];
#pragma unroll
            for (int kx = 0; kx < 9; ++kx) {
                const float4 wv = *(const float4*)&wrow[(ky * 9 + kx) * 64 + oc4];
#pragma unroll
                for (int p = 0; p < 6; ++p) {
                    const float xv = rowv[2 * p + kx];
                    acc[p][0] += xv * wv.x; acc[p][1] += xv * wv.y;
                    acc[p][2] += xv * wv.z; acc[p][3] += xv * wv.w;
                }
            }
        }
        __syncthreads();
        buf ^= 1;
    }
#undef PCAPS_STAGE
    float* pb = part + ((size_t)ict * 128 + (b0 + bb)) * 9216;
    const int oc0 = octile * 64 + oc4;
    const int cap = oc0 >> 3;
    const int d0  = oc0 & 7;
#pragma unroll
    for (int p = 0; p < 6; ++p) {
        const int pos = oy * 6 + p;
        *(float4*)&pb[((size_t)cap * 36 + pos) * 8 + d0] =
            make_float4(acc[p][0], acc[p][1], acc[p][2], acc[p][3]);
    }
}

__global__ __launch_bounds__(256) void squash_fb_kernel(
    const float* __restrict__ part, const float* __restrict__ bias,
    float* __restrict__ u, int nq)
{
    const int idx = blockIdx.x * 256 + threadIdx.x;
    if (idx >= 128 * 1152) return;
    const int i   = idx % 1152;
    const int cap = i / 36;
    float v[8];
    float n2 = 0.f;
#pragma unroll
    for (int c = 0; c < 8; ++c) {
        float s = bias[cap * 8 + c];
        for (int qq = 0; qq < nq; ++qq) s += part[(size_t)qq * 1179648 + (size_t)idx * 8 + c];
        v[c] = s;
        n2 += s * s;
    }
    const float sc = sqrtf(n2) / (1.f + n2);
#pragma unroll
    for (int c = 0; c < 8; ++c) u[(size_t)idx * 8 + c] = v[c] * sc;
}

// fallback routing (computes u_hat from u/rw inline, fp32 first pass)
__global__ __launch_bounds__(256) void routing_fb_kernel(
    const float* __restrict__ u, const float* __restrict__ rw,
    float* __restrict__ out)
{
    const int b = blockIdx.x;
    const int o = blockIdx.y;
    const int t = threadIdx.x;
    __shared__ ushort uh_s[1152 * 16];
    __shared__ float logits[1152];
    __shared__ float ebuf[1152];
    __shared__ float psum[64][17];
    __shared__ float red[8];
    __shared__ float v_s[16];
    const float* ub = u + (size_t)b * 9216;
    const float* wo = rw + (size_t)o * 147456;
    for (int i = t; i < 1152; i += 256) logits[i] = 0.f;
    __syncthreads();
    const int dq = t & 3;
    const int ig = t >> 2;
    const int d4 = dq * 4;
    for (int iter = 1; iter <= 3; ++iter) {
        float lmax = -3.0e38f;
        for (int i = t; i < 1152; i += 256) lmax = fmaxf(lmax, logits[i]);
#pragma unroll
        for (int off = 32; off; off >>= 1) lmax = fmaxf(lmax, __shfl_xor(lmax, off, 64));
        if ((t & 63) == 0) red[t >> 6] = lmax;
        __syncthreads();
        const float m = fmaxf(fmaxf(red[0], red[1]), fmaxf(red[2], red[3]));
        float ls = 0.f;
        for (int i = t; i < 1152; i += 256) {
            const float e = expf(logits[i] - m);
            ebuf[i] = e;
            ls += e;
        }
#pragma unroll
        for (int off = 32; off; off >>= 1) ls += __shfl_xor(ls, off, 64);
        if ((t & 63) == 0) red[4 + (t >> 6)] = ls;
        __syncthreads();
        const float sumE = red[4] + red[5] + red[6] + red[7];
        float4 ps = make_float4(0.f, 0.f, 0.f, 0.f);
        if (iter == 1) {
            for (int i = ig; i < 1152; i += 64) {
                const float4 uhv = uhat4(ub + i * 8, wo + (size_t)i * 128 + d4);
                __hip_bfloat16 q0 = __float2bfloat16(uhv.x);
                __hip_bfloat16 q1 = __float2bfloat16(uhv.y);
                __hip_bfloat16 q2 = __float2bfloat16(uhv.z);
                __hip_bfloat16 q3 = __float2bfloat16(uhv.w);
                ushort4 hb;
                hb.x = *(ushort*)&q0; hb.y = *(ushort*)&q1;
                hb.z = *(ushort*)&q2; hb.w = *(ushort*)&q3;
                *(ushort4*)(uh_s + i * 16 + d4) = hb;
                const float e = ebuf[i];
                ps.x += e * uhv.x; ps.y += e * uhv.y; ps.z += e * uhv.z; ps.w += e * uhv.w;
            }
        } else {
            for (int i = ig; i < 1152; i += 64) {
                const float4 uhv = uh_from_lds(uh_s, i, d4);
                const float e = ebuf[i];
                ps.x += e * uhv.x; ps.y += e * uhv.y; ps.z += e * uhv.z; ps.w += e * uhv.w;
            }
        }
        psum[ig][d4 + 0] = ps.x; psum[ig][d4 + 1] = ps.y;
        psum[ig][d4 + 2] = ps.z; psum[ig][d4 + 3] = ps.w;
        __syncthreads();
        if (t < 16) {
            float s = 0.f;
            for (int g = 0; g < 64; ++g) s += psum[g][t];
            s /= sumE;
            float qn = s * s;
            qn += __shfl_xor(qn, 1, 16); qn += __shfl_xor(qn, 2, 16);
            qn += __shfl_xor(qn, 4, 16); qn += __shfl_xor(qn, 8, 16);
            v_s[t] = s * sqrtf(qn) / (1.f + qn);
        }
        __syncthreads();
        if (iter < 3) {
            const float v0 = v_s[d4 + 0], v1 = v_s[d4 + 1];
            const float v2 = v_s[d4 + 2], v3 = v_s[d4 + 3];
            for (int i = ig; i < 1152; i += 64) {
                const float4 uhv = uh_from_lds(uh_s, i, d4);
                float pr = uhv.x * v0 + uhv.y * v1 + uhv.z * v2 + uhv.w * v3;
                pr += __shfl_xor(pr, 1, 64);
                pr += __shfl_xor(pr, 2, 64);
                if (dq == 0) logits[i] += pr;
            }
            __syncthreads();
        }
    }
    if (t < 16) out[((size_t)b * 10 + o) * 16 + t] = v_s[t];
}

// ------------------------------- launcher ----------------------------------
extern "C" void kernel_launch(void* const* d_in, const int* in_sizes, int n_in,
                              void* d_out, int out_size, void* d_ws, size_t ws_size,
                              hipStream_t stream)
{
    const float* img = (const float*)d_in[0];
    const float* c1w = (const float*)d_in[1];
    const float* c1b = (const float*)d_in[2];
    const float* pw  = (const float*)d_in[3];
    const float* pb  = (const float*)d_in[4];
    const float* rw  = (const float*)d_in[5];
    float* out = (float*)d_out;
    char* ws = (char*)d_ws;

    if (ws_size >= 116391936ULL) {
        // fast path (116,391,936 B)
        ushort* xTh  = (ushort*)(ws);                  // [0, 26,214,400)   dead after gemm9
        ushort* xTl  = (ushort*)(ws + 26214400);       // [26.2M, 52.4M)    dead after gemm9
        ushort* uh   = (ushort*)(ws);                  // [0, 47,185,920)   aliases dead xT
        ushort* Wfh  = (ushort*)(ws + 52428800);       // [52.4M, 63.2M)
        ushort* Wfl  = (ushort*)(ws + 63176704);       // [63.2M, 73.9M)
        float*  part = (float*)(ws + 73924608);        // [73.9M, 111.7M)
        float*  u    = (float*)(ws + 111673344);       // [111.7M, 116.4M)
        hipLaunchKernelGGL(conv1c_kernel, dim3(4, 128), dim3(256), 0, stream, img, c1w, c1b, xTh, xTl);
        hipLaunchKernelGGL(wsplit3_kernel, dim3(1024), dim3(256), 0, stream, pw, Wfh, Wfl);
        hipLaunchKernelGGL(gemm9_kernel, dim3(576), dim3(256), 0, stream, xTh, xTl, Wfh, Wfl, part);
        hipLaunchKernelGGL(squash_kernel, dim3(576), dim3(256), 0, stream, part, pb, u, 8);
        hipLaunchKernelGGL(uhat_kernel, dim3(72, 10), dim3(256), 0, stream, u, rw, uh);
        hipLaunchKernelGGL(routing_kernel, dim3(128, 10), dim3(256), 0, stream, uh, out);
    } else {
        // fallback: R5 fp32 direct conv (97.9 MB, proven)
        float* x    = (float*)(ws);
        float* part = (float*)(ws + 52428800);
        float* u    = (float*)(ws + 52428800 + 18874368);
        float* wT   = (float*)(ws + 52428800 + 18874368 + 4718592);
        hipLaunchKernelGGL(wtrans_kernel, dim3((4 * 256 * 81 * 16 + 255) / 256), dim3(256), 0, stream, pw, wT);
        hipLaunchKernelGGL(conv1_kernel, dim3(4, 128), dim3(256), 0, stream, img, c1w, c1b, x);
        hipLaunchKernelGGL(pcaps_kernel, dim3(32, 4, 4), dim3(384), 0, stream, x, wT, part);
        hipLaunchKernelGGL(squash_fb_kernel, dim3(576), dim3(256), 0, stream, part, pb, u, 4);
        hipLaunchKernelGGL(routing_fb_kernel, dim3(128, 10), dim3(256), 0, stream, u, rw, out);
    }
}